// Round 10
// baseline (330.868 us; speedup 1.0000x reference)
//
#include <hip/hip_runtime.h>
#include <hip/hip_bf16.h>

typedef __attribute__((ext_vector_type(8))) short short8;   // 8 x bf16 bits = 4 VGPRs
typedef __attribute__((ext_vector_type(4))) float f32x4;

#define NW 8            // waves per block (512 threads)
#define BPW 16          // batches per wave
#define BPB (NW * BPW)  // 128 batches per block

static __device__ __forceinline__ unsigned pk_bf16(float a, float b) {
    unsigned d;
    asm("v_cvt_pk_bf16_f32 %0, %1, %2" : "=v"(d) : "v"(a), "v"(b));
    return d;
}

// round-to-nearest-even bf16, returning the 16 bits
static __device__ __forceinline__ unsigned rne16(float x) {
    unsigned u = __float_as_uint(x);
    return (u + 0x7fffu + ((u >> 16) & 1u)) >> 16;
}
static __device__ __forceinline__ unsigned rne_bf16_pair(float x, float y) {
    return rne16(x) | (rne16(y) << 16);
}

static __device__ __forceinline__ short8 pack_frag(f32x4 a, f32x4 b) {
    union { unsigned u[4]; short8 s; } u;
    u.u[0] = pk_bf16(a.x, a.y);
    u.u[1] = pk_bf16(a.z, a.w);
    u.u[2] = pk_bf16(b.x, b.y);
    u.u[3] = pk_bf16(b.z, b.w);
    return u.s;
}

// Stage fragments of W (W[n][k]) into LDS. Same lane map serves as A-frag or
// B-frag: entry idx = (kt*nct + ct)*64 + lane; lane holds 8 bf16 with
// k = kt*32 + (lane>>4)*8 + j, outer = ct*16 + (lane&15).
static __device__ __forceinline__ void stage_bfrags(const float* __restrict__ w,
                                                    int row_stride, int k_off, int nct,
                                                    short8* lds, int tid) {
    const int total = 4 * nct * 64;
    for (int idx = tid; idx < total; idx += NW * 64) {
        int lane = idx & 63;
        int ct = (idx >> 6) % nct;
        int kt = idx / (64 * nct);
        int n = ct * 16 + (lane & 15);
        int k = kt * 32 + (lane >> 4) * 8;
        const float* p = w + (size_t)n * row_stride + k_off + k;
        f32x4 a = *(const f32x4*)p;
        f32x4 b = *(const f32x4*)(p + 4);
        lds[idx] = pack_frag(a, b);
    }
}

// Same, but split each element into bf16 hi + bf16 residual (hi -> lds_hi, lo -> lds_lo).
static __device__ __forceinline__ void stage_bfrags_split(const float* __restrict__ w,
                                                          int row_stride, int nct,
                                                          short8* lds_hi, short8* lds_lo,
                                                          int tid) {
    const int total = 4 * nct * 64;
    for (int idx = tid; idx < total; idx += NW * 64) {
        int lane = idx & 63;
        int ct = (idx >> 6) % nct;
        int kt = idx / (64 * nct);
        int n = ct * 16 + (lane & 15);
        int k = kt * 32 + (lane >> 4) * 8;
        const float* p = w + (size_t)n * row_stride + k;
        f32x4 a = *(const f32x4*)p;
        f32x4 b = *(const f32x4*)(p + 4);
        float xs[8] = {a.x, a.y, a.z, a.w, b.x, b.y, b.z, b.w};
        union { unsigned u[4]; short8 s; } uh, ul;
#pragma unroll
        for (int q = 0; q < 4; ++q) {
            float x = xs[2 * q], y = xs[2 * q + 1];
            unsigned hx = rne16(x), hy = rne16(y);
            uh.u[q] = hx | (hy << 16);
            ul.u[q] = rne_bf16_pair(x - __uint_as_float(hx << 16),
                                    y - __uint_as_float(hy << 16));
        }
        lds_hi[idx] = uh.s;
        lds_lo[idx] = ul.s;
    }
}

// One pipelined l-step on buffer `raw` (holds tile l, arrived):
//   1. convert raw -> af (bf16 hi), freeing raw
//   2. issue tile `lnext` loads into raw (kept in flight across this whole step
//      AND the next step -> 2 tiles / 16 KB outstanding per wave, the R10 lever)
//   3. swapped logit GEMM + 2x shfl_xor reduce
//   4. flash softmax update; o-update from af-hi (value quantized to bf16 here;
//      error budget ~0.001-0.003 at the output, see journal R10)
static __device__ __forceinline__ void stepv(int l, int lnext, const float* ap,
                                             f32x4 (&raw)[8], const short8* wlds,
                                             const uint2* hkw, const f32x4* w2lds4,
                                             int lane, int g, int sq,
                                             float& m, float& s, float (&o)[4][8]) {
    short8 af[4];
#pragma unroll
    for (int kt = 0; kt < 4; ++kt)
        af[kt] = pack_frag(raw[2 * kt], raw[2 * kt + 1]);
    if (lnext < 9) {
#pragma unroll
        for (int h = 0; h < 8; ++h)
            raw[h] = *(const f32x4*)(ap + lnext * 128 + (h >> 1) * 32 + (h & 1) * 4);
    }

    // swapped logit GEMM: acc[h-tile][b], weights A from LDS, value B in regs
    float pA = 0.f, pB = 0.f;
#pragma unroll
    for (int ct = 0; ct < 8; ++ct) {
        uint2 hkv = hkw[ct * 64 + lane];
        f32x4 acc;
        acc.x = __uint_as_float(hkv.x << 16);
        acc.y = __uint_as_float(hkv.x & 0xffff0000u);
        acc.z = __uint_as_float(hkv.y << 16);
        acc.w = __uint_as_float(hkv.y & 0xffff0000u);
#pragma unroll
        for (int kt = 0; kt < 4; ++kt)
            acc = __builtin_amdgcn_mfma_f32_16x16x32_bf16(
                wlds[(kt * 8 + ct) * 64 + lane], af[kt], acc, 0, 0, 0);
        f32x4 wv = w2lds4[ct * 4 + g];
        if (ct & 1) {
            pB += fmaxf(acc.x, 0.f) * wv.x;
            pB += fmaxf(acc.y, 0.f) * wv.y;
            pB += fmaxf(acc.z, 0.f) * wv.z;
            pB += fmaxf(acc.w, 0.f) * wv.w;
        } else {
            pA += fmaxf(acc.x, 0.f) * wv.x;
            pA += fmaxf(acc.y, 0.f) * wv.y;
            pA += fmaxf(acc.z, 0.f) * wv.z;
            pA += fmaxf(acc.w, 0.f) * wv.w;
        }
    }
    float p = pA + pB;
    p += __shfl_xor(p, 16);
    p += __shfl_xor(p, 32);
    float w = p;  // logit of batch lo, present in every lane of the column

    // flash update (masked l: no-op)
    bool valid = (l <= sq);
    float mn = valid ? fmaxf(m, w) : m;
    float c = __expf(m - mn);              // ==1 when max unchanged; ==0 on first l
    float e = valid ? __expf(w - mn) : 0.f;
    s = s * c + e;
    m = mn;
    // o-update from af-hi (raw already recycled for the prefetch)
#pragma unroll
    for (int kt = 0; kt < 4; ++kt) {
        union { short8 v; unsigned u[4]; } uh;
        uh.v = af[kt];
#pragma unroll
        for (int q = 0; q < 4; ++q) {
            float h0 = __uint_as_float(uh.u[q] << 16);
            float h1 = __uint_as_float(uh.u[q] & 0xffff0000u);
            o[kt][2 * q]     = o[kt][2 * q] * c + e * h0;
            o[kt][2 * q + 1] = o[kt][2 * q + 1] * c + e * h1;
        }
    }
}

// MEASURED launch-bounds rule on gfx950 hipcc: VGPR cap = 256/arg, independent
// of block size ((512,4)->64, (512,3)->84, (256,3)->84). (512,2) -> 128 cap.
// R10: TRUE depth-2 prefetch (rawA/rawB, issue l+2 at l's convert) -> 16 KB
// outstanding/wave at 16 waves/CU. Live set ~124 <= 128 (alo dropped; o-update
// uses bf16-hi of value). LDS 64.5 KB -> 2 blocks/CU.
__global__ __launch_bounds__(NW * 64, 2)
void mask_attn_fused(const float* __restrict__ value, const float* __restrict__ key,
                     const int* __restrict__ seq_len, const float* __restrict__ w1,
                     const float* __restrict__ b1, const float* __restrict__ w2,
                     const float* __restrict__ fcw, const float* __restrict__ fcb,
                     float* __restrict__ out, int B) {
    __shared__ short8 wlds[2048];            // 32 KiB: Wk -> Wv -> (fcw_hi|fcw_lo)
    __shared__ uint2 hklds[NW * 8 * 64];     // 32 KiB: per-wave hk^T init (bf16-pair bits)
    __shared__ f32x4 w2lds4[32];             // 512 B: w2 as f32x4[ct*4+g]

    const int tid = threadIdx.x;
    const int wave = tid >> 6;
    const int lane = tid & 63;
    const int g = lane >> 4;   // 0..3
    const int lo = lane & 15;  // 0..15

    const long long b0w = (long long)blockIdx.x * BPB + (long long)wave * BPW;
    long long vb = b0w + lo; if (vb > (long long)B - 1) vb = (long long)B - 1;

    // ---------- prologue: issue tiles 0,1 + key loads FIRST (24 KB in flight) ------
    const float* ap = value + vb * (9 * 128) + g * 8;
    f32x4 rawA[8], rawB[8];
#pragma unroll
    for (int h = 0; h < 8; ++h)
        rawA[h] = *(const f32x4*)(ap + (h >> 1) * 32 + (h & 1) * 4);
#pragma unroll
    for (int h = 0; h < 8; ++h)
        rawB[h] = *(const f32x4*)(ap + 128 + (h >> 1) * 32 + (h & 1) * 4);
    f32x4 kv[8];
    const float* kp = key + vb * 128 + g * 8;
#pragma unroll
    for (int h = 0; h < 8; ++h)
        kv[h] = *(const f32x4*)(kp + (h >> 1) * 32 + (h & 1) * 4);

    if (tid < 32) w2lds4[tid] = ((const f32x4*)w2)[tid];

    // ---------- phase 1: Wk fragments -> LDS ----------
    stage_bfrags(w1, 2 * 128, 0, 8, wlds, tid);
    __syncthreads();

    // ---------- phase 2 (swapped): C2[h][b] = b1[h] + Wk·key^T ----------
    // C/D layout: row h = ct*16 + g*4 + reg, col b = lane&15.
    {
        short8 kf[4];
#pragma unroll
        for (int kt = 0; kt < 4; ++kt)
            kf[kt] = pack_frag(kv[2 * kt], kv[2 * kt + 1]);
#pragma unroll
        for (int ct = 0; ct < 8; ++ct) {
            f32x4 acc = *(const f32x4*)(b1 + ct * 16 + g * 4);  // rows g*4..g*4+3
#pragma unroll
            for (int kt = 0; kt < 4; ++kt)
                acc = __builtin_amdgcn_mfma_f32_16x16x32_bf16(
                    wlds[(kt * 8 + ct) * 64 + lane], kf[kt], acc, 0, 0, 0);
            uint2 pk;
            pk.x = rne_bf16_pair(acc.x, acc.y);
            pk.y = rne_bf16_pair(acc.z, acc.w);
            hklds[wave * 512 + ct * 64 + lane] = pk;
        }
    }
    __syncthreads();

    // ---------- phase 3: Wv fragments -> LDS ----------
    stage_bfrags(w1, 2 * 128, 128, 8, wlds, tid);
    __syncthreads();

    const int sq = seq_len[vb];  // valid positions: l <= sq (this lane's batch = lo)
    const uint2* hkw = hklds + wave * 512;

    // ---------- phase 4: depth-2 pipelined fused l-loop ----------
    float o[4][8];
#pragma unroll
    for (int kt = 0; kt < 4; ++kt)
#pragma unroll
        for (int j = 0; j < 8; ++j) o[kt][j] = 0.f;
    float s = 0.f, m = -3e38f;

#pragma unroll 1
    for (int l = 0; l < 9; l += 2) {
        stepv(l, l + 2, ap, rawA, wlds, hkw, w2lds4, lane, g, sq, m, s, o);
        if (l + 1 < 9)
            stepv(l + 1, l + 3, ap, rawB, wlds, hkw, w2lds4, lane, g, sq, m, s, o);
    }

    // normalize; split O into bf16 hi+lo fc A-fragments (row = lo, k = kt*32+g*8+j)
    const float rs = 1.f / s;  // s>0 always: l=0 is always valid (sq >= 0)
    short8 afoh[4], afol[4];
#pragma unroll
    for (int kt = 0; kt < 4; ++kt) {
        union { unsigned u[4]; short8 v; } uh, ul;
#pragma unroll
        for (int p = 0; p < 4; ++p) {
            float x = o[kt][2 * p] * rs, y = o[kt][2 * p + 1] * rs;
            unsigned hx = rne16(x), hy = rne16(y);
            uh.u[p] = hx | (hy << 16);
            ul.u[p] = rne_bf16_pair(x - __uint_as_float(hx << 16),
                                    y - __uint_as_float(hy << 16));
        }
        afoh[kt] = uh.v;
        afol[kt] = ul.v;
    }

    __syncthreads();
    // ---------- phase 5: fcw hi/lo fragments -> LDS (hi: [0,1024), lo: [1024,2048)) --
    stage_bfrags_split(fcw, 128, 4, wlds, wlds + 1024, tid);
    __syncthreads();

    // ---------- phase 6: out = relu(O @ fcw^T + fcb), split-bf16 (3 cross terms) ----
    {
        f32x4 facc[4];
#pragma unroll
        for (int ct = 0; ct < 4; ++ct) {
            float fb = fcb[ct * 16 + lo];
            facc[ct] = (f32x4){fb, fb, fb, fb};
        }
#pragma unroll
        for (int kt = 0; kt < 4; ++kt)
#pragma unroll
            for (int ct = 0; ct < 4; ++ct) {
                short8 wh = wlds[(kt * 4 + ct) * 64 + lane];
                short8 wl = wlds[1024 + (kt * 4 + ct) * 64 + lane];
                facc[ct] = __builtin_amdgcn_mfma_f32_16x16x32_bf16(afoh[kt], wh, facc[ct], 0, 0, 0);
                facc[ct] = __builtin_amdgcn_mfma_f32_16x16x32_bf16(afol[kt], wh, facc[ct], 0, 0, 0);
                facc[ct] = __builtin_amdgcn_mfma_f32_16x16x32_bf16(afoh[kt], wl, facc[ct], 0, 0, 0);
            }
#pragma unroll
        for (int ct = 0; ct < 4; ++ct) {
            float v0 = fmaxf(facc[ct].x, 0.f), v1 = fmaxf(facc[ct].y, 0.f);
            float v2 = fmaxf(facc[ct].z, 0.f), v3 = fmaxf(facc[ct].w, 0.f);
            long long bo = b0w + g * 4;
            if (bo + 0 < B) out[(bo + 0) * 64 + ct * 16 + lo] = v0;
            if (bo + 1 < B) out[(bo + 1) * 64 + ct * 16 + lo] = v1;
            if (bo + 2 < B) out[(bo + 2) * 64 + ct * 16 + lo] = v2;
            if (bo + 3 < B) out[(bo + 3) * 64 + ct * 16 + lo] = v3;
        }
    }
}

extern "C" void kernel_launch(void* const* d_in, const int* in_sizes, int n_in,
                              void* d_out, int out_size, void* d_ws, size_t ws_size,
                              hipStream_t stream) {
    const float* value = (const float*)d_in[0];
    const float* key   = (const float*)d_in[1];
    const int*   seq   = (const int*)d_in[2];
    // d_in[3] = maxlen (unused; L == 9 fixed by reference)
    const float* w1    = (const float*)d_in[4];
    const float* b1    = (const float*)d_in[5];
    const float* w2    = (const float*)d_in[6];
    // d_in[7] = b2: softmax-invariant, dropped
    const float* fcw   = (const float*)d_in[8];
    const float* fcb   = (const float*)d_in[9];
    float* out = (float*)d_out;

    int B = in_sizes[1] / 128;
    int blocks = (B + BPB - 1) / BPB;
    mask_attn_fused<<<blocks, NW * 64, 0, stream>>>(value, key, seq, w1, b1, w2, fcw, fcb, out, B);
}

// Round 11
// 292.545 us; speedup vs baseline: 1.1310x; 1.1310x over previous
//
#include <hip/hip_runtime.h>
#include <hip/hip_bf16.h>

typedef __attribute__((ext_vector_type(8))) short short8;   // 8 x bf16 bits = 4 VGPRs
typedef __attribute__((ext_vector_type(4))) float f32x4;

#define NW 8            // waves per block (512 threads)
#define BPW 16          // batches per wave
#define BPB (NW * BPW)  // 128 batches per block

static __device__ __forceinline__ unsigned pk_bf16(float a, float b) {
    unsigned d;
    asm("v_cvt_pk_bf16_f32 %0, %1, %2" : "=v"(d) : "v"(a), "v"(b));
    return d;
}

// round-to-nearest-even bf16, returning the 16 bits
static __device__ __forceinline__ unsigned rne16(float x) {
    unsigned u = __float_as_uint(x);
    return (u + 0x7fffu + ((u >> 16) & 1u)) >> 16;
}
static __device__ __forceinline__ unsigned rne_bf16_pair(float x, float y) {
    return rne16(x) | (rne16(y) << 16);
}

static __device__ __forceinline__ short8 pack_frag(f32x4 a, f32x4 b) {
    union { unsigned u[4]; short8 s; } u;
    u.u[0] = pk_bf16(a.x, a.y);
    u.u[1] = pk_bf16(a.z, a.w);
    u.u[2] = pk_bf16(b.x, b.y);
    u.u[3] = pk_bf16(b.z, b.w);
    return u.s;
}

// Stage fragments of W (W[n][k]) into LDS. Entry idx = (kt*nct + ct)*64 + lane;
// lane holds 8 bf16 with k = kt*32 + (lane>>4)*8 + j, outer = ct*16 + (lane&15).
static __device__ __forceinline__ void stage_bfrags(const float* __restrict__ w,
                                                    int row_stride, int k_off, int nct,
                                                    short8* lds, int tid) {
    const int total = 4 * nct * 64;
    for (int idx = tid; idx < total; idx += NW * 64) {
        int lane = idx & 63;
        int ct = (idx >> 6) % nct;
        int kt = idx / (64 * nct);
        int n = ct * 16 + (lane & 15);
        int k = kt * 32 + (lane >> 4) * 8;
        const float* p = w + (size_t)n * row_stride + k_off + k;
        f32x4 a = *(const f32x4*)p;
        f32x4 b = *(const f32x4*)(p + 4);
        lds[idx] = pack_frag(a, b);
    }
}

// Same, but split each element into bf16 hi + bf16 residual (hi -> lds_hi, lo -> lds_lo).
static __device__ __forceinline__ void stage_bfrags_split(const float* __restrict__ w,
                                                          int row_stride, int nct,
                                                          short8* lds_hi, short8* lds_lo,
                                                          int tid) {
    const int total = 4 * nct * 64;
    for (int idx = tid; idx < total; idx += NW * 64) {
        int lane = idx & 63;
        int ct = (idx >> 6) % nct;
        int kt = idx / (64 * nct);
        int n = ct * 16 + (lane & 15);
        int k = kt * 32 + (lane >> 4) * 8;
        const float* p = w + (size_t)n * row_stride + k;
        f32x4 a = *(const f32x4*)p;
        f32x4 b = *(const f32x4*)(p + 4);
        float xs[8] = {a.x, a.y, a.z, a.w, b.x, b.y, b.z, b.w};
        union { unsigned u[4]; short8 s; } uh, ul;
#pragma unroll
        for (int q = 0; q < 4; ++q) {
            float x = xs[2 * q], y = xs[2 * q + 1];
            unsigned hx = rne16(x), hy = rne16(y);
            uh.u[q] = hx | (hy << 16);
            ul.u[q] = rne_bf16_pair(x - __uint_as_float(hx << 16),
                                    y - __uint_as_float(hy << 16));
        }
        lds_hi[idx] = uh.s;
        lds_lo[idx] = ul.s;
    }
}

// MEASURED launch-bounds rule on gfx950 hipcc: VGPR cap = 256/arg, independent
// of block size ((512,4)->64, (512,3)->84, (256,3)->84, (512,2)->128).
// R11: COALESCED value path. Per step the wave loads its 16 rows with 8
// instructions of 64x16B CONTIGUOUS (two full 512B rows each; 4x the old
// effective HBM granularity), converts to bf16, and transposes through a
// wave-private 4KB LDS buffer (XOR-chunk swizzle, <=2-way banks) into MFMA
// fragment ownership. hk back in registers; LDS 64.5KB -> 2 blocks/CU ->
// 16 waves/CU. Live set ~114 <= 128.
__global__ __launch_bounds__(NW * 64, 2)
void mask_attn_fused(const float* __restrict__ value, const float* __restrict__ key,
                     const int* __restrict__ seq_len, const float* __restrict__ w1,
                     const float* __restrict__ b1, const float* __restrict__ w2,
                     const float* __restrict__ fcw, const float* __restrict__ fcb,
                     float* __restrict__ out, int B) {
    __shared__ short8 wlds[2048];            // 32 KiB: Wk -> Wv -> (fcw_hi|fcw_lo)
    __shared__ unsigned vstage[NW][1024];    // 32 KiB: per-wave bf16 value tile (swizzled)
    __shared__ f32x4 w2lds4[32];             // 512 B: w2 as f32x4[ct*4+g]

    const int tid = threadIdx.x;
    const int wave = tid >> 6;
    const int lane = tid & 63;
    const int g = lane >> 4;   // 0..3
    const int lo = lane & 15;  // 0..15
    const int lrow = lane >> 5;   // 0..1 : which of the 2 rows this lane loads
    const int lcol = lane & 31;   // 0..31: 16B chunk index within the 512B row

    const long long b0w = (long long)blockIdx.x * BPB + (long long)wave * BPW;
    long long vb = b0w + lo; if (vb > (long long)B - 1) vb = (long long)B - 1;

    // ---------- prologue: COALESCED tile-0 issue (8 x 1KB contiguous) ----------
    const float* vbase = value + (size_t)b0w * 1152;  // wave's 16 rows, batch-major
    f32x4 xf[8];
#pragma unroll
    for (int j = 0; j < 8; ++j)
        xf[j] = *(const f32x4*)(vbase + (size_t)(2 * j + lrow) * 1152 + lcol * 4);

    // key loads (per-lane fragment pattern; ~10% of traffic, left as-is)
    f32x4 kv[8];
    const float* kp = key + vb * 128 + g * 8;
#pragma unroll
    for (int h = 0; h < 8; ++h)
        kv[h] = *(const f32x4*)(kp + (h >> 1) * 32 + (h & 1) * 4);

    if (tid < 32) w2lds4[tid] = ((const f32x4*)w2)[tid];

    // ---------- phase 1: Wk fragments -> LDS ----------
    stage_bfrags(w1, 2 * 128, 0, 8, wlds, tid);
    __syncthreads();

    // ---------- phase 2 (swapped): hk[h][b] = b1[h] + Wk·key^T, kept in regs ----
    // C/D layout: row h = ct*16 + g*4 + reg, col b = lane&15.
    unsigned hkp[8][2];
    {
        short8 kf[4];
#pragma unroll
        for (int kt = 0; kt < 4; ++kt)
            kf[kt] = pack_frag(kv[2 * kt], kv[2 * kt + 1]);
#pragma unroll
        for (int ct = 0; ct < 8; ++ct) {
            f32x4 acc = *(const f32x4*)(b1 + ct * 16 + g * 4);  // rows g*4..g*4+3
#pragma unroll
            for (int kt = 0; kt < 4; ++kt)
                acc = __builtin_amdgcn_mfma_f32_16x16x32_bf16(
                    wlds[(kt * 8 + ct) * 64 + lane], kf[kt], acc, 0, 0, 0);
            hkp[ct][0] = rne_bf16_pair(acc.x, acc.y);
            hkp[ct][1] = rne_bf16_pair(acc.z, acc.w);
        }
    }
    __syncthreads();

    // ---------- phase 3: Wv fragments -> LDS ----------
    stage_bfrags(w1, 2 * 128, 128, 8, wlds, tid);
    __syncthreads();

    // ---------- commit tile 0 into vstage (bf16, XOR-chunk swizzle) ----------
    // row t (256B bf16) at dword t*64; 16B chunk c stored at position c^(t&7).
    unsigned* vs = vstage[wave];
#pragma unroll
    for (int j = 0; j < 8; ++j) {
        int t = 2 * j + lrow;
        int c = lcol >> 1;
        int dw = t * 64 + ((c ^ (t & 7)) << 2) + (lcol & 1) * 2;
        uint2 pkw;
        pkw.x = pk_bf16(xf[j].x, xf[j].y);
        pkw.y = pk_bf16(xf[j].z, xf[j].w);
        *(uint2*)&vs[dw] = pkw;
    }

    const int sq = seq_len[vb];  // valid positions: l <= sq (this lane's batch = lo)

    // ---------- phase 4: pipelined fused l-loop (coalesced value path) ----------
    float o[4][8];
#pragma unroll
    for (int kt = 0; kt < 4; ++kt)
#pragma unroll
        for (int j = 0; j < 8; ++j) o[kt][j] = 0.f;
    float s = 0.f, m = -3e38f;

#pragma unroll 1
    for (int l = 0; l < 9; ++l) {
        // read this lane's B-fragments of tile l from vstage (<=2-way banks)
        short8 af[4];
#pragma unroll
        for (int kt = 0; kt < 4; ++kt) {
            int c = kt * 4 + g;
            int dw = lo * 64 + ((c ^ (lo & 7)) << 2);
            af[kt] = *reinterpret_cast<const short8*>(&vs[dw]);
        }
        // issue tile l+1's coalesced loads (in flight under the whole chain below)
        if (l + 1 < 9) {
#pragma unroll
            for (int j = 0; j < 8; ++j)
                xf[j] = *(const f32x4*)(vbase + (size_t)(2 * j + lrow) * 1152 +
                                        (l + 1) * 128 + lcol * 4);
        }

        // swapped logit GEMM: acc[h-tile][b], weights A from LDS, value B in regs
        float pA = 0.f, pB = 0.f;
#pragma unroll
        for (int ct = 0; ct < 8; ++ct) {
            f32x4 acc;
            acc.x = __uint_as_float(hkp[ct][0] << 16);
            acc.y = __uint_as_float(hkp[ct][0] & 0xffff0000u);
            acc.z = __uint_as_float(hkp[ct][1] << 16);
            acc.w = __uint_as_float(hkp[ct][1] & 0xffff0000u);
#pragma unroll
            for (int kt = 0; kt < 4; ++kt)
                acc = __builtin_amdgcn_mfma_f32_16x16x32_bf16(
                    wlds[(kt * 8 + ct) * 64 + lane], af[kt], acc, 0, 0, 0);
            f32x4 wv = w2lds4[ct * 4 + g];
            if (ct & 1) {
                pB += fmaxf(acc.x, 0.f) * wv.x;
                pB += fmaxf(acc.y, 0.f) * wv.y;
                pB += fmaxf(acc.z, 0.f) * wv.z;
                pB += fmaxf(acc.w, 0.f) * wv.w;
            } else {
                pA += fmaxf(acc.x, 0.f) * wv.x;
                pA += fmaxf(acc.y, 0.f) * wv.y;
                pA += fmaxf(acc.z, 0.f) * wv.z;
                pA += fmaxf(acc.w, 0.f) * wv.w;
            }
        }
        float p = pA + pB;
        p += __shfl_xor(p, 16);
        p += __shfl_xor(p, 32);
        float w = p;  // logit of batch lo, present in every lane of the column

        // flash update (masked l: no-op)
        bool valid = (l <= sq);
        float mn = valid ? fmaxf(m, w) : m;
        float c = __expf(m - mn);              // ==1 when max unchanged; ==0 on first l
        float e = valid ? __expf(w - mn) : 0.f;
        s = s * c + e;
        m = mn;
        // o-update from bf16 value (af); error already characterized in R10 (0.0156)
#pragma unroll
        for (int kt = 0; kt < 4; ++kt) {
            union { short8 v; unsigned u[4]; } uh;
            uh.v = af[kt];
#pragma unroll
            for (int q = 0; q < 4; ++q) {
                float h0 = __uint_as_float(uh.u[q] << 16);
                float h1 = __uint_as_float(uh.u[q] & 0xffff0000u);
                o[kt][2 * q]     = o[kt][2 * q] * c + e * h0;
                o[kt][2 * q + 1] = o[kt][2 * q + 1] * c + e * h1;
            }
        }

        // commit tile l+1 into vstage (wave-private; LDS ops in-order within wave)
        if (l + 1 < 9) {
#pragma unroll
            for (int j = 0; j < 8; ++j) {
                int t = 2 * j + lrow;
                int c2 = lcol >> 1;
                int dw = t * 64 + ((c2 ^ (t & 7)) << 2) + (lcol & 1) * 2;
                uint2 pkw;
                pkw.x = pk_bf16(xf[j].x, xf[j].y);
                pkw.y = pk_bf16(xf[j].z, xf[j].w);
                *(uint2*)&vs[dw] = pkw;
            }
        }
    }

    // normalize; split O into bf16 hi+lo fc A-fragments (row = lo, k = kt*32+g*8+j)
    const float rs = 1.f / s;  // s>0 always: l=0 is always valid (sq >= 0)
    short8 afoh[4], afol[4];
#pragma unroll
    for (int kt = 0; kt < 4; ++kt) {
        union { unsigned u[4]; short8 v; } uh, ul;
#pragma unroll
        for (int p = 0; p < 4; ++p) {
            float x = o[kt][2 * p] * rs, y = o[kt][2 * p + 1] * rs;
            unsigned hx = rne16(x), hy = rne16(y);
            uh.u[p] = hx | (hy << 16);
            ul.u[p] = rne_bf16_pair(x - __uint_as_float(hx << 16),
                                    y - __uint_as_float(hy << 16));
        }
        afoh[kt] = uh.v;
        afol[kt] = ul.v;
    }

    __syncthreads();
    // ---------- phase 5: fcw hi/lo fragments -> LDS (hi: [0,1024), lo: [1024,2048)) --
    stage_bfrags_split(fcw, 128, 4, wlds, wlds + 1024, tid);
    __syncthreads();

    // ---------- phase 6: out = relu(O @ fcw^T + fcb), split-bf16 (3 cross terms) ----
    {
        f32x4 facc[4];
#pragma unroll
        for (int ct = 0; ct < 4; ++ct) {
            float fb = fcb[ct * 16 + lo];
            facc[ct] = (f32x4){fb, fb, fb, fb};
        }
#pragma unroll
        for (int kt = 0; kt < 4; ++kt)
#pragma unroll
            for (int ct = 0; ct < 4; ++ct) {
                short8 wh = wlds[(kt * 4 + ct) * 64 + lane];
                short8 wl = wlds[1024 + (kt * 4 + ct) * 64 + lane];
                facc[ct] = __builtin_amdgcn_mfma_f32_16x16x32_bf16(afoh[kt], wh, facc[ct], 0, 0, 0);
                facc[ct] = __builtin_amdgcn_mfma_f32_16x16x32_bf16(afol[kt], wh, facc[ct], 0, 0, 0);
                facc[ct] = __builtin_amdgcn_mfma_f32_16x16x32_bf16(afoh[kt], wl, facc[ct], 0, 0, 0);
            }
#pragma unroll
        for (int ct = 0; ct < 4; ++ct) {
            float v0 = fmaxf(facc[ct].x, 0.f), v1 = fmaxf(facc[ct].y, 0.f);
            float v2 = fmaxf(facc[ct].z, 0.f), v3 = fmaxf(facc[ct].w, 0.f);
            long long bo = b0w + g * 4;
            if (bo + 0 < B) out[(bo + 0) * 64 + ct * 16 + lo] = v0;
            if (bo + 1 < B) out[(bo + 1) * 64 + ct * 16 + lo] = v1;
            if (bo + 2 < B) out[(bo + 2) * 64 + ct * 16 + lo] = v2;
            if (bo + 3 < B) out[(bo + 3) * 64 + ct * 16 + lo] = v3;
        }
    }
}

extern "C" void kernel_launch(void* const* d_in, const int* in_sizes, int n_in,
                              void* d_out, int out_size, void* d_ws, size_t ws_size,
                              hipStream_t stream) {
    const float* value = (const float*)d_in[0];
    const float* key   = (const float*)d_in[1];
    const int*   seq   = (const int*)d_in[2];
    // d_in[3] = maxlen (unused; L == 9 fixed by reference)
    const float* w1    = (const float*)d_in[4];
    const float* b1    = (const float*)d_in[5];
    const float* w2    = (const float*)d_in[6];
    // d_in[7] = b2: softmax-invariant, dropped
    const float* fcw   = (const float*)d_in[8];
    const float* fcb   = (const float*)d_in[9];
    float* out = (float*)d_out;

    int B = in_sizes[1] / 128;
    int blocks = (B + BPB - 1) / BPB;
    mask_attn_fused<<<blocks, NW * 64, 0, stream>>>(value, key, seq, w1, b1, w2, fcw, fcb, out, B);
}